// Round 1
// baseline (380.180 us; speedup 1.0000x reference)
//
#include <hip/hip_runtime.h>
#include <hip/hip_bf16.h>
#include <stdint.h>

typedef __attribute__((ext_vector_type(8))) short s8v;
typedef __attribute__((ext_vector_type(4))) float f4v;

#define T_TOT 8
#define HW 64
#define NSP 32768   // T*H*W
#define K_TOT 1024
#define M_TOT 1024

__device__ __forceinline__ unsigned short f2bf(float f) {
  unsigned int u = __float_as_uint(f);
  u += 0x7FFF + ((u >> 16) & 1);   // round-to-nearest-even
  return (unsigned short)(u >> 16);
}

// ---------------------------------------------------------------------------
// Kernel 1: depthwise 3x3x3 conv (shared kernel), bf16 cast, transpose to
// Yt[n][c]  (n = t*4096 + h*64 + w).  Block: 32 channels x 8 h-rows x 64 w
// at fixed t.  Thread: w = lane, handles 8 channels x 8 h (ring over 10 rows).
// ---------------------------------------------------------------------------
__global__ __launch_bounds__(256) void dw_t_kernel(const float* __restrict__ X,
                                                   const float* __restrict__ DW,
                                                   unsigned short* __restrict__ Yt) {
  __shared__ unsigned short tile[512][34];   // [n_local][c_local], pad 32->34 (68B rows, conflict-free b16 writes)
  const int tid = threadIdx.x;
  const int w   = tid & 63;
  const int cs  = tid >> 6;                  // 0..3
  const int c0  = blockIdx.x * 32;
  const int t   = blockIdx.y;
  const int h0  = blockIdx.z * 8;

  float kw[27];
#pragma unroll
  for (int j = 0; j < 27; ++j) kw[j] = DW[j];

  for (int k = 0; k < 8; ++k) {
    const int c = c0 + cs * 8 + k;
    const float* Xc = X + (size_t)c * (T_TOT * HW * HW);
    float acc[8] = {0.f,0.f,0.f,0.f,0.f,0.f,0.f,0.f};
#pragma unroll
    for (int r = 0; r < 10; ++r) {           // input row hh = h0-1+r
      const int hh = h0 - 1 + r;
      const bool hok = (hh >= 0) && (hh < 64);
      float xv[3][3];
#pragma unroll
      for (int tt = 0; tt < 3; ++tt) {
        const int ta = t + tt - 1;
        const bool ok = hok && (ta >= 0) && (ta < 8);
        float ctr = ok ? Xc[(ta * 64 + hh) * 64 + w] : 0.0f;
        float lef = __shfl_up(ctr, 1);
        float rig = __shfl_down(ctr, 1);
        if (w == 0)  lef = 0.0f;
        if (w == 63) rig = 0.0f;
        xv[tt][0] = lef; xv[tt][1] = ctr; xv[tt][2] = rig;
      }
#pragma unroll
      for (int kh = 0; kh < 3; ++kh) {
        const int ho = r - kh;               // compile-time after unroll
        if (ho >= 0 && ho < 8) {
          float s = 0.0f;
#pragma unroll
          for (int tt = 0; tt < 3; ++tt)
#pragma unroll
            for (int d = 0; d < 3; ++d)
              s += kw[(tt * 3 + kh) * 3 + d] * xv[tt][d];
          acc[ho] += s;
        }
      }
    }
#pragma unroll
    for (int ho = 0; ho < 8; ++ho)
      tile[ho * 64 + w][cs * 8 + k] = f2bf(acc[ho]);
  }
  __syncthreads();

  // store transposed: per iter, 4 lanes cover one n (32 c = one 64B line)
  const int nbase = t * 4096 + h0 * 64;
#pragma unroll
  for (int i = 0; i < 8; ++i) {
    const int nl = i * 64 + (tid >> 2);
    const int cd = (tid & 3);
    const unsigned int* src = (const unsigned int*)&tile[nl][cd * 8];
    uint4 v;
    v.x = src[0]; v.y = src[1]; v.z = src[2]; v.w = src[3];
    *(uint4*)&Yt[(size_t)(nbase + nl) * 1024 + c0 + cd * 8] = v;
  }
}

// ---------------------------------------------------------------------------
// Kernel 2: pointwise weight fp32 -> bf16, [1024][1024]
// ---------------------------------------------------------------------------
__global__ __launch_bounds__(256) void castw_kernel(const float* __restrict__ Wf,
                                                    unsigned short* __restrict__ Wb) {
  const int i = (blockIdx.x * 256 + threadIdx.x) * 4;
  float4 v = *(const float4*)&Wf[i];
  ushort4 o;
  o.x = f2bf(v.x); o.y = f2bf(v.y); o.z = f2bf(v.z); o.w = f2bf(v.w);
  *(ushort4*)&Wb[i] = o;
}

// ---------------------------------------------------------------------------
// Kernel 3: C[M][N] = A[M][K] * Bt[N][K]^T   (m97-style 128x128 tile, BK=32)
// A = Wb (bf16), Bt = Yt (bf16), C = out (f32).
// ---------------------------------------------------------------------------
__device__ __forceinline__ void gload_lds16(const void* g, void* lds) {
  __builtin_amdgcn_global_load_lds(
      (const __attribute__((address_space(1))) void*)(uintptr_t)g,
      (__attribute__((address_space(3))) void*)(uintptr_t)lds, 16, 0, 0);
}

__global__ __launch_bounds__(256) void gemm_kernel(const unsigned short* __restrict__ A,
                                                   const unsigned short* __restrict__ B,
                                                   float* __restrict__ C) {
  __shared__ unsigned short As[128][32];   // 8 KB
  __shared__ unsigned short Bs[128][32];   // 8 KB
  const int tid  = threadIdx.x;
  const int lane = tid & 63;
  const int wv   = tid >> 6;
  const int wr   = wv >> 1, wc = wv & 1;
  const int bn   = blockIdx.x, bm = blockIdx.y;

  f4v acc[4][4];
#pragma unroll
  for (int i = 0; i < 4; ++i)
#pragma unroll
    for (int j = 0; j < 4; ++j) acc[i][j] = (f4v){0.f, 0.f, 0.f, 0.f};

  const int r  = tid >> 2;           // tile row 0..63 (inst0) / +64 (inst1)
  const int kb = (tid & 3) * 8;      // k element offset within BK
  const unsigned short* ga0 = A + (size_t)(bm * 128 + r) * K_TOT + kb;
  const unsigned short* gb0 = B + (size_t)(bn * 128 + r) * K_TOT + kb;
  char* ldsA = (char*)(&As[0][0]) + wv * 1024;   // lane data lands at +lane*16 => linear [row][k]
  char* ldsB = (char*)(&Bs[0][0]) + wv * 1024;

  for (int kt = 0; kt < K_TOT; kt += 32) {
    __syncthreads();                 // previous compute done before overwrite
    gload_lds16(ga0 + kt,               ldsA);
    gload_lds16(ga0 + 64 * K_TOT + kt,  ldsA + 4096);
    gload_lds16(gb0 + kt,               ldsB);
    gload_lds16(gb0 + 64 * K_TOT + kt,  ldsB + 4096);
    __syncthreads();                 // compiler drains vmcnt(0) before barrier

    s8v a[4], b[4];
#pragma unroll
    for (int mf = 0; mf < 4; ++mf)
      a[mf] = *(const s8v*)&As[wr * 64 + mf * 16 + (lane & 15)][(lane >> 4) * 8];
#pragma unroll
    for (int nf = 0; nf < 4; ++nf)
      b[nf] = *(const s8v*)&Bs[wc * 64 + nf * 16 + (lane & 15)][(lane >> 4) * 8];
#pragma unroll
    for (int mf = 0; mf < 4; ++mf)
#pragma unroll
      for (int nf = 0; nf < 4; ++nf)
        acc[mf][nf] = __builtin_amdgcn_mfma_f32_16x16x32_bf16(a[mf], b[nf], acc[mf][nf], 0, 0, 0);
  }

  // epilogue: D[row=(lane>>4)*4+j][col=lane&15]
  const int rowq = (lane >> 4) * 4;
  const int colq = lane & 15;
#pragma unroll
  for (int mf = 0; mf < 4; ++mf) {
    const int row0 = bm * 128 + wr * 64 + mf * 16 + rowq;
#pragma unroll
    for (int nf = 0; nf < 4; ++nf) {
      const int col = bn * 128 + wc * 64 + nf * 16 + colq;
      float* cp = C + (size_t)row0 * NSP + col;
#pragma unroll
      for (int j = 0; j < 4; ++j) cp[(size_t)j * NSP] = acc[mf][nf][j];
    }
  }
}

// ---------------------------------------------------------------------------
extern "C" void kernel_launch(void* const* d_in, const int* in_sizes, int n_in,
                              void* d_out, int out_size, void* d_ws, size_t ws_size,
                              hipStream_t stream) {
  const float* feat = (const float*)d_in[0];
  const float* dw   = (const float*)d_in[1];
  const float* pw   = (const float*)d_in[2];
  float* out = (float*)d_out;

  unsigned short* Yt = (unsigned short*)d_ws;                 // [32768][1024] bf16, 64 MiB
  unsigned short* Wb = Yt + (size_t)NSP * 1024;               // [1024][1024] bf16, 2 MiB

  dw_t_kernel<<<dim3(32, 8, 8), dim3(256), 0, stream>>>(feat, dw, Yt);
  castw_kernel<<<dim3(1024), dim3(256), 0, stream>>>(pw, Wb);
  gemm_kernel<<<dim3(256, 8), dim3(256), 0, stream>>>(Wb, Yt, out);
}